// Round 19
// baseline (120.243 us; speedup 1.0000x reference)
//
#include <hip/hip_runtime.h>
#include <hip/hip_bf16.h>
#include <hip/hip_fp16.h>

#define C_ 8
#define B_ 32
#define G_ 2048
#define S_ 32
#define L_ 3
#define GB_ (G_ * B_)                 // 65536 items per clause

// R layout (buf0): bq-major  [c][b/4][g][4]

// ws float offsets
#define OFF_BUF0 0                     // [C][8][G][4] unnormalized R
#define OFF_MAX  524288                // cmax slots: (t*8+c)*16 -> 512 floats
#define OFF_GMAX (OFF_MAX + 512)       // gmax slots: t*16 -> 64 floats
#define OFF_DONE (OFF_MAX + 576)       // done counters: (t*8+c)*16 -> 512 uints
#define ZERO_FLOATS 1088

#define K_SCALE 144.26950408889634f    // 100 * log2(e)
#define GLN2 0.0069314718055994531f    // 0.01 * ln(2)

#define EXP2F(x) __builtin_amdgcn_exp2f(x)   // v_exp_f32: 2^x
#define LOG2F(x) __builtin_amdgcn_logf(x)    // v_log_f32: log2(x)

__device__ __forceinline__ void atomicMaxPos(float* a, float v) {
    // all values >= 0, so uint compare == float compare
    atomicMax((unsigned*)a, __float_as_uint(v));
}

__device__ __forceinline__ uint2 pack4h(float4 v) {
    __half2 a = __floats2half2_rn(v.x, v.y);
    __half2 b = __floats2half2_rn(v.z, v.w);
    uint2 q;
    q.x = *reinterpret_cast<unsigned*>(&a);
    q.y = *reinterpret_cast<unsigned*>(&b);
    return q;
}
__device__ __forceinline__ float4 unpack4h(uint2 q) {
    __half2 a = *reinterpret_cast<__half2*>(&q.x);
    __half2 b = *reinterpret_cast<__half2*>(&q.y);
    float2 fa = __half22float2(a), fb = __half22float2(b);
    return make_float4(fa.x, fa.y, fb.x, fb.y);
}

__device__ __forceinline__ float4 body3(float4 a, float4 b, float4 c) {
    float4 r;
    r.x = a.x * b.x * (c.x * K_SCALE);
    r.y = a.y * b.y * (c.y * K_SCALE);
    r.z = a.z * b.z * (c.z * K_SCALE);
    r.w = a.w * b.w * (c.w * K_SCALE);
    return r;
}
__device__ __forceinline__ float4 fmax4v(float4 a, float4 b) {
    float4 r;
    r.x = fmaxf(a.x, b.x); r.y = fmaxf(a.y, b.y);
    r.z = fmaxf(a.z, b.z); r.w = fmaxf(a.w, b.w);
    return r;
}
__device__ __forceinline__ float4 exp2m(float4 a, float4 m) {   // 2^(a-m)
    float4 r;
    r.x = EXP2F(a.x - m.x); r.y = EXP2F(a.y - m.y);
    r.z = EXP2F(a.z - m.z); r.w = EXP2F(a.w - m.w);
    return r;
}
__device__ __forceinline__ float softor2(float Rn, float rn) {
    const float M = fmaxf(Rn, rn), mn = fminf(Rn, rn);
    return M + 0.01f * __logf(1.0f + __expf((mn - M) * 100.0f));
}

// ---- fused step: clause LSE + XCD-local per-clause sync + in-register combine ----
// XCD-local mapping: c = bid&7 (== XCD), bh = (bid>>3)&7, gs = bid>>6
// 512 blocks x 256 thr, __launch_bounds__(256,2) -> 2 blocks/CU guaranteed resident.
__global__ __launch_bounds__(256, 2) void k_step(const float* __restrict__ Rbase,
                                                 int xmode,                   // 1 at t=0: Rbase = x
                                                 const int* __restrict__ I,
                                                 float* __restrict__ Rnew,    // buf0
                                                 const float* __restrict__ gmax_prev,
                                                 float* __restrict__ cmax_step,
                                                 float* __restrict__ gmax_out,
                                                 unsigned* __restrict__ done_step) {
    __shared__ unsigned sRh[G_ * 2];    // 16 KB: slice as f16x4 per g, NORMALIZED
    __shared__ float sRed[4];
    __shared__ float sCmv;

    const int tid = threadIdx.x;
    const int bid = blockIdx.x;
    const int c = bid & 7;              // clause == XCD (bid%8 round-robin)
    const int bh = (bid >> 3) & 7;
    const int gs = bid >> 6;

    const float gm = gmax_prev ? gmax_prev[0] : 0.0f;
    const float sc = (gm > 1.0f) ? (1.0f / gm) : 1.0f;

    if (xmode) {
        // transpose-stage from x: sRh half[g*4+j] = x[(bh*4+j)*G + g]  (sc == 1)
        const int j = tid >> 6;
        const int g0 = tid & 63;
        const float* xr = Rbase + (bh * 4 + j) * G_;
        __half* sH = (__half*)sRh;
#pragma unroll
        for (int k = 0; k < 32; ++k) {
            const int g = g0 + 64 * k;
            sH[g * 4 + j] = __float2half_rn(xr[g]);
        }
    } else {
        const float4* src = (const float4*)(Rbase + c * GB_ + bh * (G_ * 4));
        uint2* dst = (uint2*)sRh;
#pragma unroll
        for (int k = 0; k < 8; ++k) {
            float4 v = src[tid + k * 256];
            v.x *= sc; v.y *= sc; v.z *= sc; v.w *= sc;
            dst[tid + k * 256] = pack4h(v);
        }
    }
    __syncthreads();

    const uint2* sH2 = (const uint2*)sRh;
    const int row = gs * 256 + tid;
    const int4* p = (const int4*)(I + (c * G_ + row) * 96);

    float4 lm[8], pp[8];
#pragma unroll
    for (int ch = 0; ch < 8; ++ch) {    // 8 independent chunks of 4 substitutions
        const int4 qa = p[ch * 3 + 0], qb = p[ch * 3 + 1], qc = p[ch * 3 + 2];
        const float4 b0 = body3(unpack4h(sH2[qa.x]), unpack4h(sH2[qa.y]), unpack4h(sH2[qa.z]));
        const float4 b1 = body3(unpack4h(sH2[qa.w]), unpack4h(sH2[qb.x]), unpack4h(sH2[qb.y]));
        const float4 b2 = body3(unpack4h(sH2[qb.z]), unpack4h(sH2[qb.w]), unpack4h(sH2[qc.x]));
        const float4 b3 = body3(unpack4h(sH2[qc.y]), unpack4h(sH2[qc.z]), unpack4h(sH2[qc.w]));
        const float4 l = fmax4v(fmax4v(b0, b1), fmax4v(b2, b3));
        const float4 e0 = exp2m(b0, l), e1 = exp2m(b1, l);
        const float4 e2 = exp2m(b2, l), e3 = exp2m(b3, l);
        float4 s;
        s.x = e0.x + e1.x + e2.x + e3.x;
        s.y = e0.y + e1.y + e2.y + e3.y;
        s.z = e0.z + e1.z + e2.z + e3.z;
        s.w = e0.w + e1.w + e2.w + e3.w;
        lm[ch] = l; pp[ch] = s;
    }
    float4 M = fmax4v(fmax4v(fmax4v(lm[0], lm[1]), fmax4v(lm[2], lm[3])),
                      fmax4v(fmax4v(lm[4], lm[5]), fmax4v(lm[6], lm[7])));
    float4 sum = make_float4(0.f, 0.f, 0.f, 0.f);
#pragma unroll
    for (int ch = 0; ch < 8; ++ch) {
        const float4 w = exp2m(lm[ch], M);
        sum.x += pp[ch].x * w.x; sum.y += pp[ch].y * w.y;
        sum.z += pp[ch].z * w.z; sum.w += pp[ch].w * w.w;
    }
    float4 lse;
    lse.x = GLN2 * (M.x + LOG2F(sum.x));
    lse.y = GLN2 * (M.y + LOG2F(sum.y));
    lse.z = GLN2 * (M.z + LOG2F(sum.z));
    lse.w = GLN2 * (M.w + LOG2F(sum.w));

    // ---- per-clause max -> atomic; sync with 63 sibling blocks (same XCD) ----
    const int lane = tid & 63, wv = tid >> 6;
    float m = fmaxf(fmaxf(lse.x, lse.y), fmaxf(lse.z, lse.w));
#pragma unroll
    for (int o = 32; o; o >>= 1) m = fmaxf(m, __shfl_xor(m, o, 64));
    if (lane == 0) sRed[wv] = m;
    __syncthreads();
    if (tid == 0) {
        float a = fmaxf(fmaxf(sRed[0], sRed[1]), fmaxf(sRed[2], sRed[3]));
        atomicMaxPos(&cmax_step[c * 16], a);
        __hip_atomic_fetch_add(&done_step[c * 16], 1u, __ATOMIC_ACQ_REL,
                               __HIP_MEMORY_SCOPE_AGENT);
        while (__hip_atomic_load(&done_step[c * 16], __ATOMIC_ACQUIRE,
                                 __HIP_MEMORY_SCOPE_AGENT) < 64u)
            __builtin_amdgcn_s_sleep(1);
        const unsigned cu = __hip_atomic_load((const unsigned*)&cmax_step[c * 16],
                                              __ATOMIC_RELAXED,
                                              __HIP_MEMORY_SCOPE_AGENT);
        sCmv = __uint_as_float(cu);
    }
    __syncthreads();

    // ---- fused combine: r in registers; R_old re-read exact f32 (L2-local) ----
    const float cmv = sCmv;
    const float scr = (cmv > 1.0f) ? (1.0f / cmv) : 1.0f;
    float4 Ro;
    if (xmode) {
        Ro.x = Rbase[(bh * 4 + 0) * G_ + row];   // coalesced along row
        Ro.y = Rbase[(bh * 4 + 1) * G_ + row];
        Ro.z = Rbase[(bh * 4 + 2) * G_ + row];
        Ro.w = Rbase[(bh * 4 + 3) * G_ + row];
    } else {
        Ro = *(const float4*)(Rbase + c * GB_ + bh * (G_ * 4) + row * 4);
    }
    float4 o;
    o.x = softor2(Ro.x * sc, lse.x * scr);
    o.y = softor2(Ro.y * sc, lse.y * scr);
    o.z = softor2(Ro.z * sc, lse.z * scr);
    o.w = softor2(Ro.w * sc, lse.w * scr);
    *(float4*)(Rnew + ((c * 8 + bh) * G_ + row) * 4) = o;

    // ---- global max partial -> atomic (read by next dispatch) ----
    float mm = fmaxf(fmaxf(o.x, o.y), fmaxf(o.z, o.w));
#pragma unroll
    for (int off = 32; off; off >>= 1) mm = fmaxf(mm, __shfl_xor(mm, off, 64));
    if (lane == 0) sRed[wv] = mm;
    __syncthreads();
    if (tid == 0) {
        float a = fmaxf(fmaxf(sRed[0], sRed[1]), fmaxf(sRed[2], sRed[3]));
        atomicMaxPos(gmax_out, a);
    }
}

// ---- out: bq-major [C][8][G][4] -> [C][B][G] with final global-max scale ----
// XCD-local mapping: c = bid&7, g-chunk = bid>>3
__global__ __launch_bounds__(256) void k_out(const float* __restrict__ buf0,
                                             const float* __restrict__ gmaxslot,
                                             float* __restrict__ out) {
    __shared__ float sT[32 * 65];
    const int bid = blockIdx.x;        // 256 = 8 c x 32 g-chunks of 64
    const int c = bid & 7;
    const int g0 = (bid >> 3) << 6;
    const int tid = threadIdx.x;

    const float gm = gmaxslot[0];
    const float sc = (gm > 1.0f) ? (1.0f / gm) : 1.0f;

    const int r = tid >> 2, w = tid & 3;
#pragma unroll
    for (int k = 0; k < 8; ++k) {      // k = b-quad; reads fully contiguous per k
        sT[(k * 4 + w) * 65 + r] = buf0[((c * 8 + k) * G_ + g0 + r) * 4 + w] * sc;
    }
    __syncthreads();
#pragma unroll
    for (int k = 0; k < 8; ++k) {
        const int j = tid + k * 256;
        const int b = j >> 6, gg = j & 63;
        out[(c * B_ + b) * G_ + g0 + gg] = sT[b * 65 + gg];   // coalesced
    }
}

extern "C" void kernel_launch(void* const* d_in, const int* in_sizes, int n_in,
                              void* d_out, int out_size, void* d_ws, size_t ws_size,
                              hipStream_t stream) {
    const float* x = (const float*)d_in[0];
    const int* I = (const int*)d_in[1];
    float* out = (float*)d_out;
    float* ws = (float*)d_ws;

    float* buf0 = ws + OFF_BUF0;
    float* maxs = ws + OFF_MAX;          // cmax slots
    float* gmax = ws + OFF_GMAX;         // gmax slots
    unsigned* done = (unsigned*)(ws + OFF_DONE);

    hipMemsetAsync(ws + OFF_MAX, 0, ZERO_FLOATS * sizeof(float), stream);

    for (int t = 0; t < 4; ++t) {
        const float* Rsrc = (t == 0) ? x : buf0;
        const int xmode = (t == 0) ? 1 : 0;
        const float* gprev = (t == 0) ? nullptr : (gmax + (t - 1) * 16);
        float* cstep = maxs + t * 128;
        unsigned* dstep = done + t * 128;

        k_step<<<512, 256, 0, stream>>>(Rsrc, xmode, I, buf0, gprev, cstep,
                                        gmax + t * 16, dstep);
    }

    k_out<<<256, 256, 0, stream>>>(buf0, gmax + 48, out);
}

// Round 20
// 90.348 us; speedup vs baseline: 1.3309x; 1.3309x over previous
//
#include <hip/hip_runtime.h>
#include <hip/hip_bf16.h>
#include <hip/hip_fp16.h>

#define C_ 8
#define B_ 32
#define G_ 2048
#define S_ 32
#define L_ 3
#define GB_ (G_ * B_)                 // 65536 items per clause

// R layout (buf0, buf1): bq-major  [c][b/4][g][4]

// ws float offsets
#define OFF_BUF0 0                     // [C][8][G][4] unnormalized R (gather source)
#define OFF_BUF1 524288                // [C][8][G][4] clause lse r
#define OFF_MAX  1048576               // cmax slots: (t*8+c)*16 -> 512 floats
#define OFF_GMAX (OFF_MAX + 512)       // gmax slots: t*16 -> 64 floats
#define ZERO_FLOATS 576

#define K_SCALE 144.26950408889634f    // 100 * log2(e)
#define GLN2 0.0069314718055994531f    // 0.01 * ln(2)

#define EXP2F(x) __builtin_amdgcn_exp2f(x)   // v_exp_f32: 2^x
#define LOG2F(x) __builtin_amdgcn_logf(x)    // v_log_f32: log2(x)

__device__ __forceinline__ void atomicMaxPos(float* a, float v) {
    // all values >= 0, so uint compare == float compare
    atomicMax((unsigned*)a, __float_as_uint(v));
}

__device__ __forceinline__ uint2 pack4h(float4 v) {
    __half2 a = __floats2half2_rn(v.x, v.y);
    __half2 b = __floats2half2_rn(v.z, v.w);
    uint2 q;
    q.x = *reinterpret_cast<unsigned*>(&a);
    q.y = *reinterpret_cast<unsigned*>(&b);
    return q;
}
__device__ __forceinline__ float4 unpack4h(uint2 q) {
    __half2 a = *reinterpret_cast<__half2*>(&q.x);
    __half2 b = *reinterpret_cast<__half2*>(&q.y);
    float2 fa = __half22float2(a), fb = __half22float2(b);
    return make_float4(fa.x, fa.y, fb.x, fb.y);
}

__device__ __forceinline__ float4 body3(float4 a, float4 b, float4 c) {
    float4 r;
    r.x = a.x * b.x * (c.x * K_SCALE);
    r.y = a.y * b.y * (c.y * K_SCALE);
    r.z = a.z * b.z * (c.z * K_SCALE);
    r.w = a.w * b.w * (c.w * K_SCALE);
    return r;
}
__device__ __forceinline__ float4 fmax4v(float4 a, float4 b) {
    float4 r;
    r.x = fmaxf(a.x, b.x); r.y = fmaxf(a.y, b.y);
    r.z = fmaxf(a.z, b.z); r.w = fmaxf(a.w, b.w);
    return r;
}
__device__ __forceinline__ float4 exp2m(float4 a, float4 m) {   // 2^(a-m)
    float4 r;
    r.x = EXP2F(a.x - m.x); r.y = EXP2F(a.y - m.y);
    r.z = EXP2F(a.z - m.z); r.w = EXP2F(a.w - m.w);
    return r;
}

// ---- clause: f16-LDS-staged slice gather, chunk-parallel two-level LSE ----
// 1024 blocks x 128 thr: c = bid&7 (== XCD), bh = (bid>>3)&7, gs = bid>>6 (0..15)
// 8 blocks/CU -> 16 waves/CU (vs 8 in R18): 2x latency-hiding.
__global__ __launch_bounds__(128, 4) void k_clause(const float* __restrict__ Rbase,
                                                   int xmode,                   // 1 at t=0: Rbase = x
                                                   const int* __restrict__ I,
                                                   float* __restrict__ r_out,   // buf1
                                                   const float* __restrict__ gmax_prev,
                                                   float* __restrict__ cmax_step) {
    __shared__ unsigned sRh[G_ * 2];    // 16 KB: slice as f16x4 per g, NORMALIZED
    __shared__ float sRed[2];

    const int tid = threadIdx.x;
    const int bid = blockIdx.x;
    const int c = bid & 7;              // clause == XCD (bid%8 round-robin)
    const int bh = (bid >> 3) & 7;
    const int gs = bid >> 6;            // 0..15

    const float gm = gmax_prev ? gmax_prev[0] : 0.0f;
    const float sc = (gm > 1.0f) ? (1.0f / gm) : 1.0f;

    if (xmode) {
        // transpose-stage from x: sRh half[g*4+j] = x[(bh*4+j)*G + g]  (sc == 1)
        const int j = tid >> 5;         // 0..3
        const int g0 = tid & 31;
        const float* xr = Rbase + (bh * 4 + j) * G_;
        __half* sH = (__half*)sRh;
#pragma unroll
        for (int k = 0; k < 64; ++k) {
            const int g = g0 + 32 * k;
            sH[g * 4 + j] = __float2half_rn(xr[g]);
        }
    } else {
        const float4* src = (const float4*)(Rbase + c * GB_ + bh * (G_ * 4));
        uint2* dst = (uint2*)sRh;
#pragma unroll
        for (int k = 0; k < 16; ++k) {
            float4 v = src[tid + k * 128];
            v.x *= sc; v.y *= sc; v.z *= sc; v.w *= sc;
            dst[tid + k * 128] = pack4h(v);
        }
    }
    __syncthreads();

    const uint2* sH2 = (const uint2*)sRh;
    const int row = gs * 128 + tid;
    const int4* p = (const int4*)(I + (c * G_ + row) * 96);

    float4 lm[8], pp[8];
#pragma unroll
    for (int ch = 0; ch < 8; ++ch) {    // 8 independent chunks of 4 substitutions
        const int4 qa = p[ch * 3 + 0], qb = p[ch * 3 + 1], qc = p[ch * 3 + 2];
        const float4 b0 = body3(unpack4h(sH2[qa.x]), unpack4h(sH2[qa.y]), unpack4h(sH2[qa.z]));
        const float4 b1 = body3(unpack4h(sH2[qa.w]), unpack4h(sH2[qb.x]), unpack4h(sH2[qb.y]));
        const float4 b2 = body3(unpack4h(sH2[qb.z]), unpack4h(sH2[qb.w]), unpack4h(sH2[qc.x]));
        const float4 b3 = body3(unpack4h(sH2[qc.y]), unpack4h(sH2[qc.z]), unpack4h(sH2[qc.w]));
        const float4 l = fmax4v(fmax4v(b0, b1), fmax4v(b2, b3));
        const float4 e0 = exp2m(b0, l), e1 = exp2m(b1, l);
        const float4 e2 = exp2m(b2, l), e3 = exp2m(b3, l);
        float4 s;
        s.x = e0.x + e1.x + e2.x + e3.x;
        s.y = e0.y + e1.y + e2.y + e3.y;
        s.z = e0.z + e1.z + e2.z + e3.z;
        s.w = e0.w + e1.w + e2.w + e3.w;
        lm[ch] = l; pp[ch] = s;
    }
    // two-level combine (tree)
    float4 M = fmax4v(fmax4v(fmax4v(lm[0], lm[1]), fmax4v(lm[2], lm[3])),
                      fmax4v(fmax4v(lm[4], lm[5]), fmax4v(lm[6], lm[7])));
    float4 sum = make_float4(0.f, 0.f, 0.f, 0.f);
#pragma unroll
    for (int ch = 0; ch < 8; ++ch) {
        const float4 w = exp2m(lm[ch], M);
        sum.x += pp[ch].x * w.x; sum.y += pp[ch].y * w.y;
        sum.z += pp[ch].z * w.z; sum.w += pp[ch].w * w.w;
    }
    float4 lse;
    lse.x = GLN2 * (M.x + LOG2F(sum.x));
    lse.y = GLN2 * (M.y + LOG2F(sum.y));
    lse.z = GLN2 * (M.z + LOG2F(sum.z));
    lse.w = GLN2 * (M.w + LOG2F(sum.w));

    // write r in bq-major layout: perfect b128 store, coalesced across threads
    *(float4*)(r_out + ((c * 8 + bh) * G_ + row) * 4) = lse;

    // per-clause max partials -> atomic (block is single-clause)
    float m = fmaxf(fmaxf(lse.x, lse.y), fmaxf(lse.z, lse.w));
#pragma unroll
    for (int o = 32; o; o >>= 1) m = fmaxf(m, __shfl_xor(m, o, 64));
    const int lane = tid & 63, wv = tid >> 6;
    if (lane == 0) sRed[wv] = m;
    __syncthreads();
    if (tid == 0) {
        atomicMaxPos(&cmax_step[c * 16], fmaxf(sRed[0], sRed[1]));
    }
}

// ---- combine: acc = softor2(Rold*sc, r*scr), float4, gmax atomic ----
// XCD-local mapping: c = bid&7, blk = bid>>3 covers the clause's 64 chunks
__global__ __launch_bounds__(256, 8) void k_combine(const float* __restrict__ Rold,
                                                    int xmode,                    // 1 at t=0: Rold = x
                                                    const float* __restrict__ r_in,
                                                    float* __restrict__ Rnew,     // buf0
                                                    const float* __restrict__ gmax_prev,
                                                    const float* __restrict__ cmax_step,
                                                    float* __restrict__ gmax_out) {
    __shared__ float sRed[4];
    const int tid = threadIdx.x;
    const int c = blockIdx.x & 7;                    // clause == XCD
    const int blk = blockIdx.x >> 3;                 // 0..63
    const int i4 = c * GB_ + (blk * 256 + tid) * 4;

    const float gm = gmax_prev ? gmax_prev[0] : 0.0f;
    const float sc = (gm > 1.0f) ? (1.0f / gm) : 1.0f;
    const float cmv = cmax_step[c * 16];
    const float scr = (cmv > 1.0f) ? (1.0f / cmv) : 1.0f;

    float4 Ro;
    if (xmode) {
        const int w = i4 & (GB_ - 1);
        const int bq = w >> 13;
        const int g = (w & 8191) >> 2;
        Ro.x = Rold[(bq * 4 + 0) * G_ + g];
        Ro.y = Rold[(bq * 4 + 1) * G_ + g];
        Ro.z = Rold[(bq * 4 + 2) * G_ + g];
        Ro.w = Rold[(bq * 4 + 3) * G_ + g];
    } else {
        Ro = *(const float4*)(Rold + i4);
    }
    const float4 rv = *(const float4*)(r_in + i4);
    float4 o;
    {
        float Rn = Ro.x * sc, rn = rv.x * scr;
        float M = fmaxf(Rn, rn), mn = fminf(Rn, rn);
        o.x = M + 0.01f * __logf(1.0f + __expf((mn - M) * 100.0f));
    }
    {
        float Rn = Ro.y * sc, rn = rv.y * scr;
        float M = fmaxf(Rn, rn), mn = fminf(Rn, rn);
        o.y = M + 0.01f * __logf(1.0f + __expf((mn - M) * 100.0f));
    }
    {
        float Rn = Ro.z * sc, rn = rv.z * scr;
        float M = fmaxf(Rn, rn), mn = fminf(Rn, rn);
        o.z = M + 0.01f * __logf(1.0f + __expf((mn - M) * 100.0f));
    }
    {
        float Rn = Ro.w * sc, rn = rv.w * scr;
        float M = fmaxf(Rn, rn), mn = fminf(Rn, rn);
        o.w = M + 0.01f * __logf(1.0f + __expf((mn - M) * 100.0f));
    }
    *(float4*)(Rnew + i4) = o;

    float mm = fmaxf(fmaxf(o.x, o.y), fmaxf(o.z, o.w));
#pragma unroll
    for (int off = 32; off; off >>= 1) mm = fmaxf(mm, __shfl_xor(mm, off, 64));
    const int lane = tid & 63, wv = tid >> 6;
    if (lane == 0) sRed[wv] = mm;
    __syncthreads();
    if (tid == 0) {
        float a = fmaxf(fmaxf(sRed[0], sRed[1]), fmaxf(sRed[2], sRed[3]));
        atomicMaxPos(gmax_out, a);
    }
}

// ---- out: bq-major [C][8][G][4] -> [C][B][G] with final global-max scale ----
// XCD-local mapping: c = bid&7, g-chunk = bid>>3
__global__ __launch_bounds__(256) void k_out(const float* __restrict__ buf0,
                                             const float* __restrict__ gmaxslot,
                                             float* __restrict__ out) {
    __shared__ float sT[32 * 65];
    const int bid = blockIdx.x;        // 256 = 8 c x 32 g-chunks of 64
    const int c = bid & 7;
    const int g0 = (bid >> 3) << 6;
    const int tid = threadIdx.x;

    const float gm = gmaxslot[0];
    const float sc = (gm > 1.0f) ? (1.0f / gm) : 1.0f;

    const int r = tid >> 2, w = tid & 3;
#pragma unroll
    for (int k = 0; k < 8; ++k) {      // k = b-quad; reads fully contiguous per k
        sT[(k * 4 + w) * 65 + r] = buf0[((c * 8 + k) * G_ + g0 + r) * 4 + w] * sc;
    }
    __syncthreads();
#pragma unroll
    for (int k = 0; k < 8; ++k) {
        const int j = tid + k * 256;
        const int b = j >> 6, gg = j & 63;
        out[(c * B_ + b) * G_ + g0 + gg] = sT[b * 65 + gg];   // coalesced
    }
}

extern "C" void kernel_launch(void* const* d_in, const int* in_sizes, int n_in,
                              void* d_out, int out_size, void* d_ws, size_t ws_size,
                              hipStream_t stream) {
    const float* x = (const float*)d_in[0];
    const int* I = (const int*)d_in[1];
    float* out = (float*)d_out;
    float* ws = (float*)d_ws;

    float* buf0 = ws + OFF_BUF0;
    float* buf1 = ws + OFF_BUF1;
    float* maxs = ws + OFF_MAX;         // cmax slots
    float* gmax = ws + OFF_GMAX;        // gmax slots

    hipMemsetAsync(ws + OFF_MAX, 0, ZERO_FLOATS * sizeof(float), stream);

    for (int t = 0; t < 4; ++t) {
        const float* Rsrc = (t == 0) ? x : buf0;
        const int xmode = (t == 0) ? 1 : 0;
        const float* gprev = (t == 0) ? nullptr : (gmax + (t - 1) * 16);
        float* cstep = maxs + t * 128;

        k_clause<<<1024, 128, 0, stream>>>(Rsrc, xmode, I, buf1, gprev, cstep);
        k_combine<<<512, 256, 0, stream>>>(Rsrc, xmode, buf1, buf0, gprev, cstep,
                                           gmax + t * 16);
    }

    k_out<<<256, 256, 0, stream>>>(buf0, gmax + 48, out);
}

// Round 21
// 84.044 us; speedup vs baseline: 1.4307x; 1.0750x over previous
//
#include <hip/hip_runtime.h>
#include <hip/hip_bf16.h>
#include <hip/hip_fp16.h>

#define C_ 8
#define B_ 32
#define G_ 2048
#define S_ 32
#define L_ 3
#define GB_ (G_ * B_)                 // 65536 items per clause

// R layout (buf0, buf1): bq-major  [c][b/4][g][4]

// ws float offsets
#define OFF_BUF0 0                     // [C][8][G][4] unnormalized R (gather source)
#define OFF_BUF1 524288                // [C][8][G][4] clause lse r
#define OFF_MAX  1048576               // cmax slots: (t*8+c)*16 -> 512 floats
#define OFF_GMAX (OFF_MAX + 512)       // gmax slots: t*16 -> 64 floats
#define ZERO_FLOATS 576

#define K_SCALE 144.26950408889634f    // 100 * log2(e)
#define GLN2 0.0069314718055994531f    // 0.01 * ln(2)

#define EXP2F(x) __builtin_amdgcn_exp2f(x)   // v_exp_f32: 2^x
#define LOG2F(x) __builtin_amdgcn_logf(x)    // v_log_f32: log2(x)

__device__ __forceinline__ void atomicMaxPos(float* a, float v) {
    // all values >= 0, so uint compare == float compare
    atomicMax((unsigned*)a, __float_as_uint(v));
}

__device__ __forceinline__ uint2 pack4h(float4 v) {
    __half2 a = __floats2half2_rn(v.x, v.y);
    __half2 b = __floats2half2_rn(v.z, v.w);
    uint2 q;
    q.x = *reinterpret_cast<unsigned*>(&a);
    q.y = *reinterpret_cast<unsigned*>(&b);
    return q;
}
__device__ __forceinline__ float4 unpack4h(uint2 q) {
    __half2 a = *reinterpret_cast<__half2*>(&q.x);
    __half2 b = *reinterpret_cast<__half2*>(&q.y);
    float2 fa = __half22float2(a), fb = __half22float2(b);
    return make_float4(fa.x, fa.y, fb.x, fb.y);
}

__device__ __forceinline__ float4 body3(float4 a, float4 b, float4 c) {
    float4 r;
    r.x = a.x * b.x * (c.x * K_SCALE);
    r.y = a.y * b.y * (c.y * K_SCALE);
    r.z = a.z * b.z * (c.z * K_SCALE);
    r.w = a.w * b.w * (c.w * K_SCALE);
    return r;
}
__device__ __forceinline__ float4 fmax4v(float4 a, float4 b) {
    float4 r;
    r.x = fmaxf(a.x, b.x); r.y = fmaxf(a.y, b.y);
    r.z = fmaxf(a.z, b.z); r.w = fmaxf(a.w, b.w);
    return r;
}
__device__ __forceinline__ float4 exp2m(float4 a, float4 m) {   // 2^(a-m)
    float4 r;
    r.x = EXP2F(a.x - m.x); r.y = EXP2F(a.y - m.y);
    r.z = EXP2F(a.z - m.z); r.w = EXP2F(a.w - m.w);
    return r;
}

// ---- clause: f16-LDS-staged slice gather, chunk-parallel two-level LSE ----
// 256 blocks x 512 thr: c = bid&7 (== XCD), bh = (bid>>3)&7, gs = bid>>6 (0..3)
// 1 block/CU, 8 waves/CU (same as R18); staging redundancy halved (4 vs 8
// blocks share-stage nothing: 256 slice-stagings vs R18's 512).
__global__ __launch_bounds__(512, 2) void k_clause(const float* __restrict__ Rbase,
                                                   int xmode,                   // 1 at t=0: Rbase = x
                                                   const int* __restrict__ I,
                                                   float* __restrict__ r_out,   // buf1
                                                   const float* __restrict__ gmax_prev,
                                                   float* __restrict__ cmax_step) {
    __shared__ unsigned sRh[G_ * 2];    // 16 KB: slice as f16x4 per g, NORMALIZED
    __shared__ float sRed[8];

    const int tid = threadIdx.x;
    const int bid = blockIdx.x;
    const int c = bid & 7;              // clause == XCD (bid%8 round-robin)
    const int bh = (bid >> 3) & 7;
    const int gs = bid >> 6;            // 0..3, 512 rows each

    const float gm = gmax_prev ? gmax_prev[0] : 0.0f;
    const float sc = (gm > 1.0f) ? (1.0f / gm) : 1.0f;

    if (xmode) {
        // transpose-stage from x: sRh half[g*4+j] = x[(bh*4+j)*G + g]  (sc == 1)
        const int j = tid >> 7;         // 0..3
        const int g0 = tid & 127;
        const float* xr = Rbase + (bh * 4 + j) * G_;
        __half* sH = (__half*)sRh;
#pragma unroll
        for (int k = 0; k < 16; ++k) {
            const int g = g0 + 128 * k;
            sH[g * 4 + j] = __float2half_rn(xr[g]);
        }
    } else {
        const float4* src = (const float4*)(Rbase + c * GB_ + bh * (G_ * 4));
        uint2* dst = (uint2*)sRh;
#pragma unroll
        for (int k = 0; k < 4; ++k) {
            float4 v = src[tid + k * 512];
            v.x *= sc; v.y *= sc; v.z *= sc; v.w *= sc;
            dst[tid + k * 512] = pack4h(v);
        }
    }
    __syncthreads();

    const uint2* sH2 = (const uint2*)sRh;
    const int row = gs * 512 + tid;
    const int4* p = (const int4*)(I + (c * G_ + row) * 96);

    float4 lm[8], pp[8];
#pragma unroll
    for (int ch = 0; ch < 8; ++ch) {    // 8 independent chunks of 4 substitutions
        const int4 qa = p[ch * 3 + 0], qb = p[ch * 3 + 1], qc = p[ch * 3 + 2];
        const float4 b0 = body3(unpack4h(sH2[qa.x]), unpack4h(sH2[qa.y]), unpack4h(sH2[qa.z]));
        const float4 b1 = body3(unpack4h(sH2[qa.w]), unpack4h(sH2[qb.x]), unpack4h(sH2[qb.y]));
        const float4 b2 = body3(unpack4h(sH2[qb.z]), unpack4h(sH2[qb.w]), unpack4h(sH2[qc.x]));
        const float4 b3 = body3(unpack4h(sH2[qc.y]), unpack4h(sH2[qc.z]), unpack4h(sH2[qc.w]));
        const float4 l = fmax4v(fmax4v(b0, b1), fmax4v(b2, b3));
        const float4 e0 = exp2m(b0, l), e1 = exp2m(b1, l);
        const float4 e2 = exp2m(b2, l), e3 = exp2m(b3, l);
        float4 s;
        s.x = e0.x + e1.x + e2.x + e3.x;
        s.y = e0.y + e1.y + e2.y + e3.y;
        s.z = e0.z + e1.z + e2.z + e3.z;
        s.w = e0.w + e1.w + e2.w + e3.w;
        lm[ch] = l; pp[ch] = s;
    }
    // two-level combine (tree)
    float4 M = fmax4v(fmax4v(fmax4v(lm[0], lm[1]), fmax4v(lm[2], lm[3])),
                      fmax4v(fmax4v(lm[4], lm[5]), fmax4v(lm[6], lm[7])));
    float4 sum = make_float4(0.f, 0.f, 0.f, 0.f);
#pragma unroll
    for (int ch = 0; ch < 8; ++ch) {
        const float4 w = exp2m(lm[ch], M);
        sum.x += pp[ch].x * w.x; sum.y += pp[ch].y * w.y;
        sum.z += pp[ch].z * w.z; sum.w += pp[ch].w * w.w;
    }
    float4 lse;
    lse.x = GLN2 * (M.x + LOG2F(sum.x));
    lse.y = GLN2 * (M.y + LOG2F(sum.y));
    lse.z = GLN2 * (M.z + LOG2F(sum.z));
    lse.w = GLN2 * (M.w + LOG2F(sum.w));

    // write r in bq-major layout: perfect b128 store, coalesced across threads
    *(float4*)(r_out + ((c * 8 + bh) * G_ + row) * 4) = lse;

    // per-clause max partials -> atomic (block is single-clause)
    float m = fmaxf(fmaxf(lse.x, lse.y), fmaxf(lse.z, lse.w));
#pragma unroll
    for (int o = 32; o; o >>= 1) m = fmaxf(m, __shfl_xor(m, o, 64));
    const int lane = tid & 63, wv = tid >> 6;
    if (lane == 0) sRed[wv] = m;
    __syncthreads();
    if (tid == 0) {
        float a = sRed[0];
#pragma unroll
        for (int k = 1; k < 8; ++k) a = fmaxf(a, sRed[k]);
        atomicMaxPos(&cmax_step[c * 16], a);
    }
}

// ---- combine: acc = softor2(Rold*sc, r*scr), float4, gmax atomic ----
// XCD-local mapping: c = bid&7, blk = bid>>3 covers the clause's 64 chunks
__global__ __launch_bounds__(256, 8) void k_combine(const float* __restrict__ Rold,
                                                    int xmode,                    // 1 at t=0: Rold = x
                                                    const float* __restrict__ r_in,
                                                    float* __restrict__ Rnew,     // buf0
                                                    const float* __restrict__ gmax_prev,
                                                    const float* __restrict__ cmax_step,
                                                    float* __restrict__ gmax_out) {
    __shared__ float sRed[4];
    const int tid = threadIdx.x;
    const int c = blockIdx.x & 7;                    // clause == XCD
    const int blk = blockIdx.x >> 3;                 // 0..63
    const int i4 = c * GB_ + (blk * 256 + tid) * 4;

    const float gm = gmax_prev ? gmax_prev[0] : 0.0f;
    const float sc = (gm > 1.0f) ? (1.0f / gm) : 1.0f;
    const float cmv = cmax_step[c * 16];
    const float scr = (cmv > 1.0f) ? (1.0f / cmv) : 1.0f;

    float4 Ro;
    if (xmode) {
        const int w = i4 & (GB_ - 1);
        const int bq = w >> 13;
        const int g = (w & 8191) >> 2;
        Ro.x = Rold[(bq * 4 + 0) * G_ + g];
        Ro.y = Rold[(bq * 4 + 1) * G_ + g];
        Ro.z = Rold[(bq * 4 + 2) * G_ + g];
        Ro.w = Rold[(bq * 4 + 3) * G_ + g];
    } else {
        Ro = *(const float4*)(Rold + i4);
    }
    const float4 rv = *(const float4*)(r_in + i4);
    float4 o;
    {
        float Rn = Ro.x * sc, rn = rv.x * scr;
        float M = fmaxf(Rn, rn), mn = fminf(Rn, rn);
        o.x = M + 0.01f * __logf(1.0f + __expf((mn - M) * 100.0f));
    }
    {
        float Rn = Ro.y * sc, rn = rv.y * scr;
        float M = fmaxf(Rn, rn), mn = fminf(Rn, rn);
        o.y = M + 0.01f * __logf(1.0f + __expf((mn - M) * 100.0f));
    }
    {
        float Rn = Ro.z * sc, rn = rv.z * scr;
        float M = fmaxf(Rn, rn), mn = fminf(Rn, rn);
        o.z = M + 0.01f * __logf(1.0f + __expf((mn - M) * 100.0f));
    }
    {
        float Rn = Ro.w * sc, rn = rv.w * scr;
        float M = fmaxf(Rn, rn), mn = fminf(Rn, rn);
        o.w = M + 0.01f * __logf(1.0f + __expf((mn - M) * 100.0f));
    }
    *(float4*)(Rnew + i4) = o;

    float mm = fmaxf(fmaxf(o.x, o.y), fmaxf(o.z, o.w));
#pragma unroll
    for (int off = 32; off; off >>= 1) mm = fmaxf(mm, __shfl_xor(mm, off, 64));
    const int lane = tid & 63, wv = tid >> 6;
    if (lane == 0) sRed[wv] = mm;
    __syncthreads();
    if (tid == 0) {
        float a = fmaxf(fmaxf(sRed[0], sRed[1]), fmaxf(sRed[2], sRed[3]));
        atomicMaxPos(gmax_out, a);
    }
}

// ---- out: bq-major [C][8][G][4] -> [C][B][G] with final global-max scale ----
// XCD-local mapping: c = bid&7, g-chunk = bid>>3
__global__ __launch_bounds__(256) void k_out(const float* __restrict__ buf0,
                                             const float* __restrict__ gmaxslot,
                                             float* __restrict__ out) {
    __shared__ float sT[32 * 65];
    const int bid = blockIdx.x;        // 256 = 8 c x 32 g-chunks of 64
    const int c = bid & 7;
    const int g0 = (bid >> 3) << 6;
    const int tid = threadIdx.x;

    const float gm = gmaxslot[0];
    const float sc = (gm > 1.0f) ? (1.0f / gm) : 1.0f;

    const int r = tid >> 2, w = tid & 3;
#pragma unroll
    for (int k = 0; k < 8; ++k) {      // k = b-quad; reads fully contiguous per k
        sT[(k * 4 + w) * 65 + r] = buf0[((c * 8 + k) * G_ + g0 + r) * 4 + w] * sc;
    }
    __syncthreads();
#pragma unroll
    for (int k = 0; k < 8; ++k) {
        const int j = tid + k * 256;
        const int b = j >> 6, gg = j & 63;
        out[(c * B_ + b) * G_ + g0 + gg] = sT[b * 65 + gg];   // coalesced
    }
}

extern "C" void kernel_launch(void* const* d_in, const int* in_sizes, int n_in,
                              void* d_out, int out_size, void* d_ws, size_t ws_size,
                              hipStream_t stream) {
    const float* x = (const float*)d_in[0];
    const int* I = (const int*)d_in[1];
    float* out = (float*)d_out;
    float* ws = (float*)d_ws;

    float* buf0 = ws + OFF_BUF0;
    float* buf1 = ws + OFF_BUF1;
    float* maxs = ws + OFF_MAX;         // cmax slots
    float* gmax = ws + OFF_GMAX;        // gmax slots

    hipMemsetAsync(ws + OFF_MAX, 0, ZERO_FLOATS * sizeof(float), stream);

    for (int t = 0; t < 4; ++t) {
        const float* Rsrc = (t == 0) ? x : buf0;
        const int xmode = (t == 0) ? 1 : 0;
        const float* gprev = (t == 0) ? nullptr : (gmax + (t - 1) * 16);
        float* cstep = maxs + t * 128;

        k_clause<<<256, 512, 0, stream>>>(Rsrc, xmode, I, buf1, gprev, cstep);
        k_combine<<<512, 256, 0, stream>>>(Rsrc, xmode, buf1, buf0, gprev, cstep,
                                           gmax + t * 16);
    }

    k_out<<<256, 256, 0, stream>>>(buf0, gmax + 48, out);
}